// Round 9
// baseline (501.243 us; speedup 1.0000x reference)
//
#include <hip/hip_runtime.h>
#include <hip/hip_fp16.h>

#define NN 20000
#define NE 320000
#define NG 256
#define EB 1250   // NE / 256 exactly
#define SCB 80    // scan blocks per edge set (80*256 = 20480 >= NN)

// ---------------- CSR build ----------------

__global__ __launch_bounds__(256) void hist_both_kernel(
    const int* __restrict__ dis_dst, const int* __restrict__ edge_dst,
    int* __restrict__ cnt_d, int* __restrict__ cnt_e) {
  int b = blockIdx.x;
  if (b < EB) {
    int e = b * 256 + threadIdx.x;
    atomicAdd(&cnt_d[dis_dst[e]], 1);
  } else {
    int e = (b - EB) * 256 + threadIdx.x;
    atomicAdd(&cnt_e[edge_dst[e]], 1);
  }
}

__global__ __launch_bounds__(256) void scan_local_kernel(
    const int* __restrict__ cnt_d, const int* __restrict__ cnt_e,
    int* __restrict__ rp_d, int* __restrict__ rp_e, int* __restrict__ totals) {
  int b = blockIdx.x;
  const int* counts = (b < SCB) ? cnt_d : cnt_e;
  int* rp = (b < SCB) ? rp_d : rp_e;
  int base = ((b < SCB) ? b : b - SCB) * 256;
  int t = threadIdx.x;
  int lane = t & 63;
  int w = t >> 6;
  int idx = base + t;
  int v = (idx < NN) ? counts[idx] : 0;
  int incl = v;
#pragma unroll
  for (int off = 1; off < 64; off <<= 1) {
    int g = __shfl_up(incl, off);
    if (lane >= off) incl += g;
  }
  __shared__ int wsum[4];
  if (lane == 63) wsum[w] = incl;
  __syncthreads();
  int woff = 0;
  for (int j = 0; j < 4; ++j)
    if (j < w) woff += wsum[j];
  if (idx < NN) rp[idx] = woff + incl - v;
  if (t == 255) totals[b] = woff + incl;
}

__global__ __launch_bounds__(256) void scan_apply_kernel(
    const int* __restrict__ totals, int* __restrict__ rp_d,
    int* __restrict__ rp_e) {
  int b = blockIdx.x;
  int set = (b < SCB) ? 0 : 1;
  int lb = (b < SCB) ? b : b - SCB;
  const int* tt = totals + set * SCB;
  int t = threadIdx.x;
  __shared__ int soff, stot;
  if (t < 64) {
    int lane = t;
    int v = (lane < lb) ? tt[lane] : 0;
    int a = (lane < SCB) ? tt[lane] : 0;
    int l2 = 64 + lane;
    if (l2 < SCB) {
      if (l2 < lb) v += tt[l2];
      a += tt[l2];
    }
#pragma unroll
    for (int off = 1; off < 64; off <<= 1) {
      v += __shfl_xor(v, off);
      a += __shfl_xor(a, off);
    }
    if (lane == 0) { soff = v; stot = a; }
  }
  __syncthreads();
  int* rp = (set == 0) ? rp_d : rp_e;
  int idx = lb * 256 + t;
  if (idx < NN) rp[idx] += soff;
  if (t == 0 && lb == SCB - 1) rp[NN] = stot;
}

__global__ __launch_bounds__(256) void scatter_both_kernel(
    const int* __restrict__ dis_idx, const int* __restrict__ edge_idx,
    const int* __restrict__ rp_d, const int* __restrict__ rp_e,
    int* __restrict__ cur_d, int* __restrict__ cur_e,
    int* __restrict__ s_d, int* __restrict__ s_e) {
  int b = blockIdx.x;
  if (b < EB) {
    int e = b * 256 + threadIdx.x;
    int d = dis_idx[NE + e];
    int pos = rp_d[d] + atomicAdd(&cur_d[d], 1);
    s_d[pos] = dis_idx[e];
  } else {
    int e = (b - EB) * 256 + threadIdx.x;
    int d = edge_idx[NE + e];
    int pos = rp_e[d] + atomicAdd(&cur_e[d], 1);
    s_e[pos] = edge_idx[e];
  }
}

// ---------------- first GEMM + attention sums ----------------

__global__ __launch_bounds__(256) void gemm_attn_kernel(
    const float* __restrict__ x, const float* __restrict__ W,
    const float* __restrict__ att_src, const float* __restrict__ att_dst,
    __half* __restrict__ h, float* __restrict__ a_src, float* __restrict__ a_dst) {
  __shared__ float ws[64 * 64];
  int t = threadIdx.x;
  int lr = t >> 6;
  int c = t & 63;
  int n = blockIdx.x * 4 + lr;
  const float4* W4 = (const float4*)W;
  float4* ws4 = (float4*)ws;
  for (int k = t; k < 1024; k += 256) ws4[k] = W4[k];
  float xv = x[n * 64 + c];
  __syncthreads();
  float acc = 0.f;
#pragma unroll
  for (int k = 0; k < 64; ++k) {
    float xk = __shfl(xv, k);
    acc = fmaf(xk, ws[k * 64 + c], acc);
  }
  h[n * 64 + c] = __float2half(acc);
  float ts = acc * att_src[c];
  float td = acc * att_dst[c];
#pragma unroll
  for (int off = 1; off < 8; off <<= 1) {
    ts += __shfl_xor(ts, off);
    td += __shfl_xor(td, off);
  }
  if ((c & 7) == 0) {
    a_src[n * 8 + (c >> 3)] = ts;
    a_dst[n * 8 + (c >> 3)] = td;
  }
}

// ---------------- fused agg, edge-slot layout ----------------
// lane = (es in [0,4), p in [0,16)). Lane owns channels 4p..4p+3 (8B fp16).
// One h-gather instruction fetches 4 edges' full 128B rows.
// Attention weights exp(leaky(a_src[s]+a_dst[i])) precomputed without
// redundancy (one gather + one exp per 8 edges x 8 heads for H=8; per 64
// edges for H=1), broadcast to consumers via shfl.
template <int H, bool RELU, int HN>
__global__ __launch_bounds__(256) void agg_fused_kernel(
    const __half* __restrict__ h, const float* __restrict__ a_src,
    const float* __restrict__ a_dst, const int* __restrict__ rowptr,
    const int* __restrict__ srcs, const float* __restrict__ bias,
    __half* __restrict__ out_h, float* __restrict__ out_f,
    const float* __restrict__ Wn, const float* __restrict__ asn,
    const float* __restrict__ adn, float* __restrict__ a_src_n,
    float* __restrict__ a_dst_n) {
  extern __shared__ float ws[];
  int t = threadIdx.x;
  int lane = t & 63;
  int es = lane >> 4;
  int p = lane & 15;
  if (HN != 0) {
    const float4* W4 = (const float4*)Wn;
    float4* ws4 = (float4*)ws;
    for (int k = t; k < 1024; k += 256) ws4[k] = W4[k];
    __syncthreads();
  }
  const int i = blockIdx.x * 4 + (t >> 6);

  int j0 = rowptr[i], je = rowptr[i + 1];
  int deg = je - j0;
  // a_dst in weight layout (head = lane&7 for H=8)
  float adw = (H == 8) ? a_dst[i * 8 + (lane & 7)] : a_dst[i];
  // self-loop values (head = p>>1 for H=8)
  float as_self = (H == 8) ? a_src[i * 8 + (p >> 1)] : a_src[i];
  float ad_self = (H == 8) ? __shfl(adw, p >> 1) : adw;
  float2 hs = *(const float2*)&h[i * 64 + 4 * p];
  float4 bv = *(const float4*)&bias[4 * p];

  float denom = 0.f, c0 = 0.f, c1 = 0.f, c2 = 0.f, c3 = 0.f;

  for (int b0 = 0; b0 < deg; b0 += 64) {
    int blkn = deg - b0;
    if (blkn > 64) blkn = 64;
    int li = j0 + b0 + lane;
    if (li > je - 1) li = je - 1;
    int sIdx = srcs[li];
    float wwAll;
    if (H == 1) {
      float av = a_src[sIdx];
      float ll = av + adw;
      ll = (ll > 0.f) ? ll : 0.2f * ll;
      wwAll = (lane < blkn) ? __expf(ll) : 0.f;
    }
    for (int r0 = 0; r0 < blkn; r0 += 16) {
      float wwA, wwB;
      if (H == 8) {
        int r8 = lane >> 3;
        int sA = __shfl(sIdx, r0 + r8);
        int sB = __shfl(sIdx, r0 + 8 + r8);
        float avA = a_src[sA * 8 + (lane & 7)];
        float avB = a_src[sB * 8 + (lane & 7)];
        float llA = avA + adw;
        llA = (llA > 0.f) ? llA : 0.2f * llA;
        float llB = avB + adw;
        llB = (llB > 0.f) ? llB : 0.2f * llB;
        wwA = (r0 + r8 < blkn) ? __expf(llA) : 0.f;
        wwB = (r0 + 8 + r8 < blkn) ? __expf(llB) : 0.f;
      }
#pragma unroll
      for (int u = 0; u < 4; ++u) {
        int r = r0 + 4 * u + es;
        int sv = __shfl(sIdx, r);
        float ww;
        if (H == 8) {
          // batch A holds edges r0..r0+7 at lane (idx*8 + head)
          int srcLane = ((u & 1) ? (4 + es) : es) * 8 + (p >> 1);
          ww = __shfl((u < 2) ? wwA : wwB, srcLane);
        } else {
          ww = __shfl(wwAll, r);
        }
        float2 hv = *(const float2*)&h[sv * 64 + 4 * p];
        float2 f01 = __half22float2(*(__half2*)&hv.x);
        float2 f23 = __half22float2(*(__half2*)&hv.y);
        denom += ww;
        c0 = fmaf(ww, f01.x, c0);
        c1 = fmaf(ww, f01.y, c1);
        c2 = fmaf(ww, f23.x, c2);
        c3 = fmaf(ww, f23.y, c3);
      }
    }
  }
  // reduce over 4 edge-slot groups
  denom += __shfl_xor(denom, 16);
  denom += __shfl_xor(denom, 32);
  c0 += __shfl_xor(c0, 16); c0 += __shfl_xor(c0, 32);
  c1 += __shfl_xor(c1, 16); c1 += __shfl_xor(c1, 32);
  c2 += __shfl_xor(c2, 16); c2 += __shfl_xor(c2, 32);
  c3 += __shfl_xor(c3, 16); c3 += __shfl_xor(c3, 32);
  // self loop
  {
    float l = as_self + ad_self;
    l = (l > 0.f) ? l : 0.2f * l;
    float w = __expf(l);
    float2 f01 = __half22float2(*(__half2*)&hs.x);
    float2 f23 = __half22float2(*(__half2*)&hs.y);
    denom += w;
    c0 = fmaf(w, f01.x, c0);
    c1 = fmaf(w, f01.y, c1);
    c2 = fmaf(w, f23.x, c2);
    c3 = fmaf(w, f23.y, c3);
  }
  float inv = 1.f / denom;
  float o0 = c0 * inv + bv.x;
  float o1 = c1 * inv + bv.y;
  float o2 = c2 * inv + bv.z;
  float o3 = c3 * inv + bv.w;
  if (RELU) {
    o0 = fmaxf(o0, 0.f); o1 = fmaxf(o1, 0.f);
    o2 = fmaxf(o2, 0.f); o3 = fmaxf(o3, 0.f);
  }
  if (HN == 0) {
    if (es == 0) *(float4*)&out_f[i * 64 + 4 * p] = make_float4(o0, o1, o2, o3);
    return;
  }
  // fused next GEMM: k split over es (16 serial steps), reduce over es.
  float a0 = 0.f, a1 = 0.f, a2 = 0.f, a3 = 0.f;
#pragma unroll
  for (int kk = 0; kk < 16; ++kk) {
    int k = 16 * es + kk;
    int srcLane = 4 * es + (kk >> 2);  // lane (es'=0, p'=k>>2)
    float ok = __shfl((kk & 3) == 0 ? o0 : (kk & 3) == 1 ? o1
                      : (kk & 3) == 2 ? o2 : o3, srcLane);
    float4 wv = *(const float4*)&ws[k * 64 + 4 * p];
    a0 = fmaf(ok, wv.x, a0);
    a1 = fmaf(ok, wv.y, a1);
    a2 = fmaf(ok, wv.z, a2);
    a3 = fmaf(ok, wv.w, a3);
  }
  a0 += __shfl_xor(a0, 16); a0 += __shfl_xor(a0, 32);
  a1 += __shfl_xor(a1, 16); a1 += __shfl_xor(a1, 32);
  a2 += __shfl_xor(a2, 16); a2 += __shfl_xor(a2, 32);
  a3 += __shfl_xor(a3, 16); a3 += __shfl_xor(a3, 32);
  if (es == 0) {
    float2 st;
    *(__half2*)&st.x = __floats2half2_rn(a0, a1);
    *(__half2*)&st.y = __floats2half2_rn(a2, a3);
    *(float2*)&out_h[i * 64 + 4 * p] = st;
  }
  float4 anv = *(const float4*)&asn[4 * p];
  float4 adv = *(const float4*)&adn[4 * p];
  float ts = a0 * anv.x + a1 * anv.y + a2 * anv.z + a3 * anv.w;
  float td = a0 * adv.x + a1 * adv.y + a2 * adv.z + a3 * adv.w;
  if (HN == 8) {
    ts += __shfl_xor(ts, 1);
    td += __shfl_xor(td, 1);
    if (es == 0 && (p & 1) == 0) {
      a_src_n[i * 8 + (p >> 1)] = ts;
      a_dst_n[i * 8 + (p >> 1)] = td;
    }
  } else {
#pragma unroll
    for (int off = 1; off < 16; off <<= 1) {
      ts += __shfl_xor(ts, off);
      td += __shfl_xor(td, off);
    }
    if (lane == 0) {
      a_src_n[i] = ts;
      a_dst_n[i] = td;
    }
  }
}

// ---------------- fused pool + readout: one block per graph ----------------

__global__ __launch_bounds__(256) void poolread_kernel(
    const float* __restrict__ xF, const int* __restrict__ batch,
    const float* __restrict__ Wm1, const float* __restrict__ bm1,
    const float* __restrict__ Wm2, const float* __restrict__ bm2,
    float* __restrict__ out) {
  __shared__ float sred[4][64];
  __shared__ int se[2];
  int g = blockIdx.x;
  int t = threadIdx.x;
  int w = t >> 6, c = t & 63;
  if (t < 2) {
    int target = g + t;
    int lo = 0, hi = NN;
    while (lo < hi) {
      int m = (lo + hi) >> 1;
      if (batch[m] < target) lo = m + 1;
      else hi = m;
    }
    se[t] = lo;
  }
  __syncthreads();
  int s = se[0], e = se[1];
  float acc = 0.f;
  for (int n = s + w; n < e; n += 4) acc += xF[n * 64 + c];
  sred[w][c] = acc;
  __syncthreads();
  if (w == 0) {
    float v = sred[0][c] + sred[1][c] + sred[2][c] + sred[3][c];
    float cv = fmaxf((float)(e - s), 1.f);
    float gv = v / cv;
    float a1 = 0.f;
#pragma unroll
    for (int k = 0; k < 64; ++k) {
      float bk = __shfl(gv, k);
      if (c < 32) a1 = fmaf(bk, Wm1[k * 32 + c], a1);
    }
    float m = 0.f;
    if (c < 32) {
      float hid = fmaxf(a1 + bm1[c], 0.f);
      m = hid * Wm2[c];
    }
#pragma unroll
    for (int off = 32; off >= 1; off >>= 1) m += __shfl_xor(m, off);
    if (c == 0) out[g] = m + bm2[0];
  }
}

// ---------------- launch ----------------

extern "C" void kernel_launch(void* const* d_in, const int* in_sizes, int n_in,
                              void* d_out, int out_size, void* d_ws, size_t ws_size,
                              hipStream_t stream) {
  const float* x0       = (const float*)d_in[0];
  const int*   edge_idx = (const int*)d_in[1];
  const int*   batch    = (const int*)d_in[3];
  const int*   dis_idx  = (const int*)d_in[6];
  const float* W1  = (const float*)d_in[7];
  const float* as1 = (const float*)d_in[8];
  const float* ad1 = (const float*)d_in[9];
  const float* b1  = (const float*)d_in[10];
  const float* W2  = (const float*)d_in[11];
  const float* as2 = (const float*)d_in[12];
  const float* ad2 = (const float*)d_in[13];
  const float* b2  = (const float*)d_in[14];
  const float* Wm1 = (const float*)d_in[19];
  const float* bm1 = (const float*)d_in[20];
  const float* Wm2 = (const float*)d_in[21];
  const float* bm2 = (const float*)d_in[22];
  float* out = (float*)d_out;

  char* ws = (char*)d_ws;
  size_t off = 0;
  auto alloc = [&](size_t bytes) {
    void* p = ws + off;
    off += (bytes + 255) & ~(size_t)255;
    return p;
  };
  __half* hA   = (__half*)alloc(NN * 64 * 2);
  __half* hB   = (__half*)alloc(NN * 64 * 2);
  float* xF    = (float*)alloc(NN * 64 * 4);
  float* asA   = (float*)alloc(NN * 8 * 4);
  float* adA   = (float*)alloc(NN * 8 * 4);
  float* asB   = (float*)alloc(NN * 8 * 4);
  float* adB   = (float*)alloc(NN * 8 * 4);
  int* rp_d    = (int*)alloc((NN + 1) * 4);
  int* s_d     = (int*)alloc(NE * 4);
  int* rp_e    = (int*)alloc((NN + 1) * 4);
  int* s_e     = (int*)alloc(NE * 4);
  int* totals  = (int*)alloc(2 * SCB * 4);
  char* zero0  = ws + off;
  int* cnt_d   = (int*)alloc(NN * 4);
  int* cur_d   = (int*)alloc(NN * 4);
  int* cnt_e   = (int*)alloc(NN * 4);
  int* cur_e   = (int*)alloc(NN * 4);
  size_t zbytes = (size_t)((char*)(ws + off) - zero0);

  const size_t SH = 64 * 64 * sizeof(float);
  const int NB = NN / 4;  // 5000

  hipMemsetAsync(zero0, 0, zbytes, stream);
  hist_both_kernel<<<2 * EB, 256, 0, stream>>>(dis_idx + NE, edge_idx + NE,
                                               cnt_d, cnt_e);
  scan_local_kernel<<<2 * SCB, 256, 0, stream>>>(cnt_d, cnt_e, rp_d, rp_e, totals);
  scan_apply_kernel<<<2 * SCB, 256, 0, stream>>>(totals, rp_d, rp_e);
  scatter_both_kernel<<<2 * EB, 256, 0, stream>>>(dis_idx, edge_idx, rp_d, rp_e,
                                                  cur_d, cur_e, s_d, s_e);

  gemm_attn_kernel<<<NB, 256, 0, stream>>>(x0, W1, as1, ad1, hA, asA, adA);

  for (int k = 0; k < 12; ++k) {
    const int* rp = (((k >> 1) & 1) == 0) ? rp_d : rp_e;
    const int* ss = (((k >> 1) & 1) == 0) ? s_d : s_e;
    if ((k & 1) == 0) {
      agg_fused_kernel<8, true, 1><<<NB, 256, SH, stream>>>(
          hA, asA, adA, rp, ss, b1, hB, nullptr, W2, as2, ad2, asB, adB);
    } else if (k < 11) {
      agg_fused_kernel<1, false, 8><<<NB, 256, SH, stream>>>(
          hB, asB, adB, rp, ss, b2, hA, nullptr, W1, as1, ad1, asA, adA);
    } else {
      agg_fused_kernel<1, false, 0><<<NB, 256, 0, stream>>>(
          hB, asB, adB, rp, ss, b2, nullptr, xF, nullptr, nullptr, nullptr,
          nullptr, nullptr);
    }
  }

  poolread_kernel<<<NG, 256, 0, stream>>>(xF, batch, Wm1, bm1, Wm2, bm2, out);
}

// Round 10
// 396.620 us; speedup vs baseline: 1.2638x; 1.2638x over previous
//
#include <hip/hip_runtime.h>
#include <hip/hip_fp16.h>

#define NN 20000
#define NE 320000
#define NG 256
#define HB 313    // hist/scatter blocks per edge set: 313*1024 >= NE
#define SCB 80    // scan blocks per edge set (80*256 = 20480 >= NN)

// ---------------- CSR build ----------------

// grid = 2*HB, 256 threads, 4 edges/thread.
__global__ __launch_bounds__(256) void hist_both_kernel(
    const int* __restrict__ dis_dst, const int* __restrict__ edge_dst,
    int* __restrict__ cnt_d, int* __restrict__ cnt_e) {
  int b = blockIdx.x;
  const int* dst = (b < HB) ? dis_dst : edge_dst;
  int* cnt = (b < HB) ? cnt_d : cnt_e;
  int base = ((b < HB) ? b : b - HB) * 1024 + threadIdx.x;
#pragma unroll
  for (int u = 0; u < 4; ++u) {
    int e = base + u * 256;
    if (e < NE) atomicAdd(&cnt[dst[e]], 1);
  }
}

__global__ __launch_bounds__(256) void scan_local_kernel(
    const int* __restrict__ cnt_d, const int* __restrict__ cnt_e,
    int* __restrict__ rp_d, int* __restrict__ rp_e, int* __restrict__ totals) {
  int b = blockIdx.x;
  const int* counts = (b < SCB) ? cnt_d : cnt_e;
  int* rp = (b < SCB) ? rp_d : rp_e;
  int base = ((b < SCB) ? b : b - SCB) * 256;
  int t = threadIdx.x;
  int lane = t & 63;
  int w = t >> 6;
  int idx = base + t;
  int v = (idx < NN) ? counts[idx] : 0;
  int incl = v;
#pragma unroll
  for (int off = 1; off < 64; off <<= 1) {
    int g = __shfl_up(incl, off);
    if (lane >= off) incl += g;
  }
  __shared__ int wsum[4];
  if (lane == 63) wsum[w] = incl;
  __syncthreads();
  int woff = 0;
  for (int j = 0; j < 4; ++j)
    if (j < w) woff += wsum[j];
  if (idx < NN) rp[idx] = woff + incl - v;
  if (t == 255) totals[b] = woff + incl;
}

__global__ __launch_bounds__(256) void scan_apply_kernel(
    const int* __restrict__ totals, int* __restrict__ rp_d,
    int* __restrict__ rp_e) {
  int b = blockIdx.x;
  int set = (b < SCB) ? 0 : 1;
  int lb = (b < SCB) ? b : b - SCB;
  const int* tt = totals + set * SCB;
  int t = threadIdx.x;
  __shared__ int soff, stot;
  if (t < 64) {
    int lane = t;
    int v = (lane < lb) ? tt[lane] : 0;
    int a = (lane < SCB) ? tt[lane] : 0;
    int l2 = 64 + lane;
    if (l2 < SCB) {
      if (l2 < lb) v += tt[l2];
      a += tt[l2];
    }
#pragma unroll
    for (int off = 1; off < 64; off <<= 1) {
      v += __shfl_xor(v, off);
      a += __shfl_xor(a, off);
    }
    if (lane == 0) { soff = v; stot = a; }
  }
  __syncthreads();
  int* rp = (set == 0) ? rp_d : rp_e;
  int idx = lb * 256 + t;
  if (idx < NN) rp[idx] += soff;
  if (t == 0 && lb == SCB - 1) rp[NN] = stot;
}

// grid = 2*HB, 256 threads, 4 edges/thread.
__global__ __launch_bounds__(256) void scatter_both_kernel(
    const int* __restrict__ dis_idx, const int* __restrict__ edge_idx,
    const int* __restrict__ rp_d, const int* __restrict__ rp_e,
    int* __restrict__ cur_d, int* __restrict__ cur_e,
    int* __restrict__ s_d, int* __restrict__ s_e) {
  int b = blockIdx.x;
  const int* ei = (b < HB) ? dis_idx : edge_idx;
  const int* rp = (b < HB) ? rp_d : rp_e;
  int* cur = (b < HB) ? cur_d : cur_e;
  int* sout = (b < HB) ? s_d : s_e;
  int base = ((b < HB) ? b : b - HB) * 1024 + threadIdx.x;
#pragma unroll
  for (int u = 0; u < 4; ++u) {
    int e = base + u * 256;
    if (e < NE) {
      int d = ei[NE + e];
      int pos = rp[d] + atomicAdd(&cur[d], 1);
      sout[pos] = ei[e];
    }
  }
}

// ---------------- first GEMM + attention sums (512 thr, 8 rows) ------------

__global__ __launch_bounds__(512) void gemm_attn_kernel(
    const float* __restrict__ x, const float* __restrict__ W,
    const float* __restrict__ att_src, const float* __restrict__ att_dst,
    __half* __restrict__ h, float* __restrict__ a_src, float* __restrict__ a_dst) {
  __shared__ float ws[64 * 64];
  int t = threadIdx.x;
  int lr = t >> 6;
  int c = t & 63;
  int n = blockIdx.x * 8 + lr;
  const float4* W4 = (const float4*)W;
  float4* ws4 = (float4*)ws;
  for (int k = t; k < 1024; k += 512) ws4[k] = W4[k];
  float xv = x[n * 64 + c];
  __syncthreads();
  float acc = 0.f;
#pragma unroll
  for (int k = 0; k < 64; ++k) {
    float xk = __shfl(xv, k);
    acc = fmaf(xk, ws[k * 64 + c], acc);
  }
  h[n * 64 + c] = __float2half(acc);
  float ts = acc * att_src[c];
  float td = acc * att_dst[c];
#pragma unroll
  for (int off = 1; off < 8; off <<= 1) {
    ts += __shfl_xor(ts, off);
    td += __shfl_xor(td, off);
  }
  if ((c & 7) == 0) {
    a_src[n * 8 + (c >> 3)] = ts;
    a_dst[n * 8 + (c >> 3)] = td;
  }
}

// ---------------- fused agg: TWO nodes per wave, 512-thread blocks ----------
// Wave code identical to the round-8 winner; only geometry changed
// (16 nodes/block -> 1250 blocks per dispatch).
template <int H, bool RELU, int HN>
__global__ __launch_bounds__(512) void agg_fused_kernel(
    const __half* __restrict__ h, const float* __restrict__ a_src,
    const float* __restrict__ a_dst, const int* __restrict__ rowptr,
    const int* __restrict__ srcs, const float* __restrict__ bias,
    __half* __restrict__ out_h, float* __restrict__ out_f,
    const float* __restrict__ Wn, const float* __restrict__ asn,
    const float* __restrict__ adn, float* __restrict__ a_src_n,
    float* __restrict__ a_dst_n) {
  extern __shared__ float ws[];
  int t = threadIdx.x;
  int lane = t & 63;
  int half = lane >> 5;
  int p = lane & 31;
  if (HN != 0) {
    const float4* W4 = (const float4*)Wn;
    float4* ws4 = (float4*)ws;
    for (int k = t; k < 1024; k += 512) ws4[k] = W4[k];
    __syncthreads();
  }
  const int hd = (H == 8) ? (p >> 2) : 0;
  const int iA = blockIdx.x * 16 + (t >> 6) * 2;
  const int iB = iA + 1;

  // independent early loads
  int j0A = rowptr[iA], jeA = rowptr[iA + 1], jeB = rowptr[iB + 1];
  int j0B = jeA;
  float adA = a_dst[iA * H + hd], adB = a_dst[iB * H + hd];
  float asSA = a_src[iA * H + hd], asSB = a_src[iB * H + hd];
  __half2 hsA = *(const __half2*)&h[iA * 64 + 2 * p];
  __half2 hsB = *(const __half2*)&h[iB * 64 + 2 * p];

  int degA = jeA - j0A, degB = jeB - j0B;
  int sIdxA = 0, sIdxB = 0;
  if (degA > 0) {
    int li = j0A + lane;
    if (li > jeA - 1) li = jeA - 1;
    sIdxA = srcs[li];
  }
  if (degB > 0) {
    int li = j0B + lane;
    if (li > jeB - 1) li = jeB - 1;
    sIdxB = srcs[li];
  }
  int bA = degA < 64 ? degA : 64;
  int bB = degB < 64 ? degB : 64;
  int mx = bA > bB ? bA : bB;

  float denA = 0.f, axA = 0.f, ayA = 0.f;
  float denB = 0.f, axB = 0.f, ayB = 0.f;

  for (int r0 = 0; r0 < mx; r0 += 16) {
    int svA[8], svB[8];
    float asvA[8], asvB[8];
    __half2 hvA[8], hvB[8];
    bool doA = r0 < bA, doB = r0 < bB;
    if (doA) {
#pragma unroll
      for (int u = 0; u < 8; ++u) svA[u] = __shfl(sIdxA, r0 + 2 * u + half);
#pragma unroll
      for (int u = 0; u < 8; ++u) asvA[u] = a_src[svA[u] * H + hd];
#pragma unroll
      for (int u = 0; u < 8; ++u)
        hvA[u] = *(const __half2*)&h[svA[u] * 64 + 2 * p];
    }
    if (doB) {
#pragma unroll
      for (int u = 0; u < 8; ++u) svB[u] = __shfl(sIdxB, r0 + 2 * u + half);
#pragma unroll
      for (int u = 0; u < 8; ++u) asvB[u] = a_src[svB[u] * H + hd];
#pragma unroll
      for (int u = 0; u < 8; ++u)
        hvB[u] = *(const __half2*)&h[svB[u] * 64 + 2 * p];
    }
    if (doA) {
#pragma unroll
      for (int u = 0; u < 8; ++u) {
        int r = r0 + 2 * u + half;
        float ll = asvA[u] + adA;
        ll = (ll > 0.f) ? ll : 0.2f * ll;
        float ww = __expf(ll);
        ww = (r < bA) ? ww : 0.f;
        float2 hf = __half22float2(hvA[u]);
        denA += ww;
        axA = fmaf(ww, hf.x, axA);
        ayA = fmaf(ww, hf.y, ayA);
      }
    }
    if (doB) {
#pragma unroll
      for (int u = 0; u < 8; ++u) {
        int r = r0 + 2 * u + half;
        float ll = asvB[u] + adB;
        ll = (ll > 0.f) ? ll : 0.2f * ll;
        float ww = __expf(ll);
        ww = (r < bB) ? ww : 0.f;
        float2 hf = __half22float2(hvB[u]);
        denB += ww;
        axB = fmaf(ww, hf.x, axB);
        ayB = fmaf(ww, hf.y, ayB);
      }
    }
  }
  // rare tail (deg > 64)
  for (int b0 = 64; b0 < degA; b0 += 64) {
    int li = j0A + b0 + lane;
    if (li > jeA - 1) li = jeA - 1;
    int sIdx = srcs[li];
    int blkn = degA - b0;
    if (blkn > 64) blkn = 64;
    for (int r0 = 0; r0 < blkn; r0 += 16) {
#pragma unroll
      for (int u = 0; u < 8; ++u) {
        int r = r0 + 2 * u + half;
        int s = __shfl(sIdx, r);
        float ll = a_src[s * H + hd] + adA;
        ll = (ll > 0.f) ? ll : 0.2f * ll;
        float ww = __expf(ll);
        ww = (r < blkn) ? ww : 0.f;
        float2 hf = __half22float2(*(const __half2*)&h[s * 64 + 2 * p]);
        denA += ww;
        axA = fmaf(ww, hf.x, axA);
        ayA = fmaf(ww, hf.y, ayA);
      }
    }
  }
  for (int b0 = 64; b0 < degB; b0 += 64) {
    int li = j0B + b0 + lane;
    if (li > jeB - 1) li = jeB - 1;
    int sIdx = srcs[li];
    int blkn = degB - b0;
    if (blkn > 64) blkn = 64;
    for (int r0 = 0; r0 < blkn; r0 += 16) {
#pragma unroll
      for (int u = 0; u < 8; ++u) {
        int r = r0 + 2 * u + half;
        int s = __shfl(sIdx, r);
        float ll = a_src[s * H + hd] + adB;
        ll = (ll > 0.f) ? ll : 0.2f * ll;
        float ww = __expf(ll);
        ww = (r < blkn) ? ww : 0.f;
        float2 hf = __half22float2(*(const __half2*)&h[s * 64 + 2 * p]);
        denB += ww;
        axB = fmaf(ww, hf.x, axB);
        ayB = fmaf(ww, hf.y, ayB);
      }
    }
  }

  // combine halves
  denA += __shfl_xor(denA, 32);
  axA += __shfl_xor(axA, 32);
  ayA += __shfl_xor(ayA, 32);
  denB += __shfl_xor(denB, 32);
  axB += __shfl_xor(axB, 32);
  ayB += __shfl_xor(ayB, 32);
  // self loops
  {
    float l = asSA + adA;
    l = (l > 0.f) ? l : 0.2f * l;
    float w = __expf(l);
    float2 hf = __half22float2(hsA);
    denA += w;
    axA = fmaf(w, hf.x, axA);
    ayA = fmaf(w, hf.y, ayA);
    l = asSB + adB;
    l = (l > 0.f) ? l : 0.2f * l;
    w = __expf(l);
    hf = __half22float2(hsB);
    denB += w;
    axB = fmaf(w, hf.x, axB);
    ayB = fmaf(w, hf.y, ayB);
  }
  float bx = bias[2 * p], by = bias[2 * p + 1];
  float invA = 1.f / denA, invB = 1.f / denB;
  float oxA = axA * invA + bx, oyA = ayA * invA + by;
  float oxB = axB * invB + bx, oyB = ayB * invB + by;
  if (RELU) {
    oxA = fmaxf(oxA, 0.f); oyA = fmaxf(oyA, 0.f);
    oxB = fmaxf(oxB, 0.f); oyB = fmaxf(oyB, 0.f);
  }
  if (HN == 0) {
    if (half == 0) {
      *(float2*)&out_f[iA * 64 + 2 * p] = make_float2(oxA, oyA);
      *(float2*)&out_f[iB * 64 + 2 * p] = make_float2(oxB, oyB);
    }
    return;
  }
  // fused next GEMM, split across halves (32 iters) + interleaved A/B
  const float2* ws2 = (const float2*)ws;
  float a2xA = 0.f, a2yA = 0.f, a2xB = 0.f, a2yB = 0.f;
#pragma unroll
  for (int kk = 0; kk < 32; ++kk) {
    int k = half * 32 + kk;
    float okA = __shfl((k & 1) ? oyA : oxA, k >> 1);
    float okB = __shfl((k & 1) ? oyB : oxB, k >> 1);
    float2 wv = ws2[k * 32 + p];
    a2xA = fmaf(okA, wv.x, a2xA);
    a2yA = fmaf(okA, wv.y, a2yA);
    a2xB = fmaf(okB, wv.x, a2xB);
    a2yB = fmaf(okB, wv.y, a2yB);
  }
  a2xA += __shfl_xor(a2xA, 32);
  a2yA += __shfl_xor(a2yA, 32);
  a2xB += __shfl_xor(a2xB, 32);
  a2yB += __shfl_xor(a2yB, 32);
  if (half == 0) {
    *(__half2*)&out_h[iA * 64 + 2 * p] = __floats2half2_rn(a2xA, a2yA);
    *(__half2*)&out_h[iB * 64 + 2 * p] = __floats2half2_rn(a2xB, a2yB);
  }
  float anx = asn[2 * p], any = asn[2 * p + 1];
  float adx = adn[2 * p], ady = adn[2 * p + 1];
  float tsA = a2xA * anx + a2yA * any;
  float tdA = a2xA * adx + a2yA * ady;
  float tsB = a2xB * anx + a2yB * any;
  float tdB = a2xB * adx + a2yB * ady;
  const int gsp = (HN == 8) ? 4 : 32;
#pragma unroll
  for (int off = 1; off < gsp; off <<= 1) {
    tsA += __shfl_xor(tsA, off);
    tdA += __shfl_xor(tdA, off);
    tsB += __shfl_xor(tsB, off);
    tdB += __shfl_xor(tdB, off);
  }
  if (half == 0 && (p & (gsp - 1)) == 0) {
    int hdn = p / gsp;
    a_src_n[iA * HN + hdn] = tsA;
    a_dst_n[iA * HN + hdn] = tdA;
    a_src_n[iB * HN + hdn] = tsB;
    a_dst_n[iB * HN + hdn] = tdB;
  }
}

// ---------------- fused pool + readout: one block per graph ----------------

__global__ __launch_bounds__(256) void poolread_kernel(
    const float* __restrict__ xF, const int* __restrict__ batch,
    const float* __restrict__ Wm1, const float* __restrict__ bm1,
    const float* __restrict__ Wm2, const float* __restrict__ bm2,
    float* __restrict__ out) {
  __shared__ float sred[4][64];
  __shared__ int se[2];
  int g = blockIdx.x;
  int t = threadIdx.x;
  int w = t >> 6, c = t & 63;
  if (t < 2) {
    int target = g + t;
    int lo = 0, hi = NN;
    while (lo < hi) {
      int m = (lo + hi) >> 1;
      if (batch[m] < target) lo = m + 1;
      else hi = m;
    }
    se[t] = lo;
  }
  __syncthreads();
  int s = se[0], e = se[1];
  float acc = 0.f;
  for (int n = s + w; n < e; n += 4) acc += xF[n * 64 + c];
  sred[w][c] = acc;
  __syncthreads();
  if (w == 0) {
    float v = sred[0][c] + sred[1][c] + sred[2][c] + sred[3][c];
    float cv = fmaxf((float)(e - s), 1.f);
    float gv = v / cv;
    float a1 = 0.f;
#pragma unroll
    for (int k = 0; k < 64; ++k) {
      float bk = __shfl(gv, k);
      if (c < 32) a1 = fmaf(bk, Wm1[k * 32 + c], a1);
    }
    float m = 0.f;
    if (c < 32) {
      float hid = fmaxf(a1 + bm1[c], 0.f);
      m = hid * Wm2[c];
    }
#pragma unroll
    for (int off = 32; off >= 1; off >>= 1) m += __shfl_xor(m, off);
    if (c == 0) out[g] = m + bm2[0];
  }
}

// ---------------- launch ----------------

extern "C" void kernel_launch(void* const* d_in, const int* in_sizes, int n_in,
                              void* d_out, int out_size, void* d_ws, size_t ws_size,
                              hipStream_t stream) {
  const float* x0       = (const float*)d_in[0];
  const int*   edge_idx = (const int*)d_in[1];
  const int*   batch    = (const int*)d_in[3];
  const int*   dis_idx  = (const int*)d_in[6];
  const float* W1  = (const float*)d_in[7];
  const float* as1 = (const float*)d_in[8];
  const float* ad1 = (const float*)d_in[9];
  const float* b1  = (const float*)d_in[10];
  const float* W2  = (const float*)d_in[11];
  const float* as2 = (const float*)d_in[12];
  const float* ad2 = (const float*)d_in[13];
  const float* b2  = (const float*)d_in[14];
  const float* Wm1 = (const float*)d_in[19];
  const float* bm1 = (const float*)d_in[20];
  const float* Wm2 = (const float*)d_in[21];
  const float* bm2 = (const float*)d_in[22];
  float* out = (float*)d_out;

  char* ws = (char*)d_ws;
  size_t off = 0;
  auto alloc = [&](size_t bytes) {
    void* p = ws + off;
    off += (bytes + 255) & ~(size_t)255;
    return p;
  };
  __half* hA   = (__half*)alloc(NN * 64 * 2);
  __half* hB   = (__half*)alloc(NN * 64 * 2);
  float* xF    = (float*)alloc(NN * 64 * 4);
  float* asA   = (float*)alloc(NN * 8 * 4);
  float* adA   = (float*)alloc(NN * 8 * 4);
  float* asB   = (float*)alloc(NN * 8 * 4);
  float* adB   = (float*)alloc(NN * 8 * 4);
  int* rp_d    = (int*)alloc((NN + 1) * 4);
  int* s_d     = (int*)alloc(NE * 4);
  int* rp_e    = (int*)alloc((NN + 1) * 4);
  int* s_e     = (int*)alloc(NE * 4);
  int* totals  = (int*)alloc(2 * SCB * 4);
  char* zero0  = ws + off;
  int* cnt_d   = (int*)alloc(NN * 4);
  int* cur_d   = (int*)alloc(NN * 4);
  int* cnt_e   = (int*)alloc(NN * 4);
  int* cur_e   = (int*)alloc(NN * 4);
  size_t zbytes = (size_t)((char*)(ws + off) - zero0);

  const size_t SH = 64 * 64 * sizeof(float);
  const int NBG = NN / 8;   // 2500 (gemm, 512 thr)
  const int NBA = NN / 16;  // 1250 (agg, 512 thr, 2 nodes/wave)

  hipMemsetAsync(zero0, 0, zbytes, stream);
  hist_both_kernel<<<2 * HB, 256, 0, stream>>>(dis_idx + NE, edge_idx + NE,
                                               cnt_d, cnt_e);
  scan_local_kernel<<<2 * SCB, 256, 0, stream>>>(cnt_d, cnt_e, rp_d, rp_e, totals);
  scan_apply_kernel<<<2 * SCB, 256, 0, stream>>>(totals, rp_d, rp_e);
  scatter_both_kernel<<<2 * HB, 256, 0, stream>>>(dis_idx, edge_idx, rp_d, rp_e,
                                                  cur_d, cur_e, s_d, s_e);

  gemm_attn_kernel<<<NBG, 512, 0, stream>>>(x0, W1, as1, ad1, hA, asA, adA);

  for (int k = 0; k < 12; ++k) {
    const int* rp = (((k >> 1) & 1) == 0) ? rp_d : rp_e;
    const int* ss = (((k >> 1) & 1) == 0) ? s_d : s_e;
    if ((k & 1) == 0) {
      agg_fused_kernel<8, true, 1><<<NBA, 512, SH, stream>>>(
          hA, asA, adA, rp, ss, b1, hB, nullptr, W2, as2, ad2, asB, adB);
    } else if (k < 11) {
      agg_fused_kernel<1, false, 8><<<NBA, 512, SH, stream>>>(
          hB, asB, adB, rp, ss, b2, hA, nullptr, W1, as1, ad1, asA, adA);
    } else {
      agg_fused_kernel<1, false, 0><<<NBA, 512, 0, stream>>>(
          hB, asB, adB, rp, ss, b2, nullptr, xF, nullptr, nullptr, nullptr,
          nullptr, nullptr);
    }
  }

  poolread_kernel<<<NG, 256, 0, stream>>>(xF, batch, Wm1, bm1, Wm2, bm2, out);
}

// Round 11
// 396.300 us; speedup vs baseline: 1.2648x; 1.0008x over previous
//
#include <hip/hip_runtime.h>
#include <hip/hip_fp16.h>

#define NN 20000
#define NE 320000
#define NG 256
#define HB 313    // hist/scatter blocks per edge set: 313*1024 >= NE
#define SCB 80    // scan blocks per edge set (80*256 = 20480 >= NN)

// ---------------- CSR build ----------------

__global__ __launch_bounds__(256) void hist_both_kernel(
    const int* __restrict__ dis_dst, const int* __restrict__ edge_dst,
    int* __restrict__ cnt_d, int* __restrict__ cnt_e) {
  int b = blockIdx.x;
  const int* dst = (b < HB) ? dis_dst : edge_dst;
  int* cnt = (b < HB) ? cnt_d : cnt_e;
  int base = ((b < HB) ? b : b - HB) * 1024 + threadIdx.x;
#pragma unroll
  for (int u = 0; u < 4; ++u) {
    int e = base + u * 256;
    if (e < NE) atomicAdd(&cnt[dst[e]], 1);
  }
}

__global__ __launch_bounds__(256) void scan_local_kernel(
    const int* __restrict__ cnt_d, const int* __restrict__ cnt_e,
    int* __restrict__ rp_d, int* __restrict__ rp_e, int* __restrict__ totals) {
  int b = blockIdx.x;
  const int* counts = (b < SCB) ? cnt_d : cnt_e;
  int* rp = (b < SCB) ? rp_d : rp_e;
  int base = ((b < SCB) ? b : b - SCB) * 256;
  int t = threadIdx.x;
  int lane = t & 63;
  int w = t >> 6;
  int idx = base + t;
  int v = (idx < NN) ? counts[idx] : 0;
  int incl = v;
#pragma unroll
  for (int off = 1; off < 64; off <<= 1) {
    int g = __shfl_up(incl, off);
    if (lane >= off) incl += g;
  }
  __shared__ int wsum[4];
  if (lane == 63) wsum[w] = incl;
  __syncthreads();
  int woff = 0;
  for (int j = 0; j < 4; ++j)
    if (j < w) woff += wsum[j];
  if (idx < NN) rp[idx] = woff + incl - v;
  if (t == 255) totals[b] = woff + incl;
}

__global__ __launch_bounds__(256) void scan_apply_kernel(
    const int* __restrict__ totals, int* __restrict__ rp_d,
    int* __restrict__ rp_e) {
  int b = blockIdx.x;
  int set = (b < SCB) ? 0 : 1;
  int lb = (b < SCB) ? b : b - SCB;
  const int* tt = totals + set * SCB;
  int t = threadIdx.x;
  __shared__ int soff, stot;
  if (t < 64) {
    int lane = t;
    int v = (lane < lb) ? tt[lane] : 0;
    int a = (lane < SCB) ? tt[lane] : 0;
    int l2 = 64 + lane;
    if (l2 < SCB) {
      if (l2 < lb) v += tt[l2];
      a += tt[l2];
    }
#pragma unroll
    for (int off = 1; off < 64; off <<= 1) {
      v += __shfl_xor(v, off);
      a += __shfl_xor(a, off);
    }
    if (lane == 0) { soff = v; stot = a; }
  }
  __syncthreads();
  int* rp = (set == 0) ? rp_d : rp_e;
  int idx = lb * 256 + t;
  if (idx < NN) rp[idx] += soff;
  if (t == 0 && lb == SCB - 1) rp[NN] = stot;
}

__global__ __launch_bounds__(256) void scatter_both_kernel(
    const int* __restrict__ dis_idx, const int* __restrict__ edge_idx,
    const int* __restrict__ rp_d, const int* __restrict__ rp_e,
    int* __restrict__ cur_d, int* __restrict__ cur_e,
    int* __restrict__ s_d, int* __restrict__ s_e) {
  int b = blockIdx.x;
  const int* ei = (b < HB) ? dis_idx : edge_idx;
  const int* rp = (b < HB) ? rp_d : rp_e;
  int* cur = (b < HB) ? cur_d : cur_e;
  int* sout = (b < HB) ? s_d : s_e;
  int base = ((b < HB) ? b : b - HB) * 1024 + threadIdx.x;
#pragma unroll
  for (int u = 0; u < 4; ++u) {
    int e = base + u * 256;
    if (e < NE) {
      int d = ei[NE + e];
      int pos = rp[d] + atomicAdd(&cur[d], 1);
      sout[pos] = ei[e];
    }
  }
}

// ---------------- first GEMM + attention sums (512 thr, 8 rows) ------------

__global__ __launch_bounds__(512) void gemm_attn_kernel(
    const float* __restrict__ x, const float* __restrict__ W,
    const float* __restrict__ att_src, const float* __restrict__ att_dst,
    __half* __restrict__ h, float* __restrict__ a_src, float* __restrict__ a_dst) {
  __shared__ float ws[64 * 64];
  int t = threadIdx.x;
  int lr = t >> 6;
  int c = t & 63;
  int n = blockIdx.x * 8 + lr;
  const float4* W4 = (const float4*)W;
  float4* ws4 = (float4*)ws;
  for (int k = t; k < 1024; k += 512) ws4[k] = W4[k];
  float xv = x[n * 64 + c];
  __syncthreads();
  float acc = 0.f;
#pragma unroll
  for (int k = 0; k < 64; ++k) {
    float xk = __shfl(xv, k);
    acc = fmaf(xk, ws[k * 64 + c], acc);
  }
  h[n * 64 + c] = __float2half(acc);
  float ts = acc * att_src[c];
  float td = acc * att_dst[c];
#pragma unroll
  for (int off = 1; off < 8; off <<= 1) {
    ts += __shfl_xor(ts, off);
    td += __shfl_xor(td, off);
  }
  if ((c & 7) == 0) {
    a_src[n * 8 + (c >> 3)] = ts;
    a_dst[n * 8 + (c >> 3)] = td;
  }
}

// ---------------- fused agg: octet layout, 2 nodes/wave ----------------
// lane = (q in [0,8) edge slot, p8 in [0,8) channel octet == head for H=8).
// One float4 gather = 8 fp16 channels; one instruction covers 8 edges' rows.
// Per 16 edges per node: 2 shfl + 2 a_src gathers + 2 h gathers + 2 exp.
template <int H, bool RELU, int HN>
__global__ __launch_bounds__(512) void agg_fused_kernel(
    const __half* __restrict__ h, const float* __restrict__ a_src,
    const float* __restrict__ a_dst, const int* __restrict__ rowptr,
    const int* __restrict__ srcs, const float* __restrict__ bias,
    __half* __restrict__ out_h, float* __restrict__ out_f,
    const float* __restrict__ Wn, const float* __restrict__ asn,
    const float* __restrict__ adn, float* __restrict__ a_src_n,
    float* __restrict__ a_dst_n) {
  extern __shared__ float ws[];
  int t = threadIdx.x;
  int lane = t & 63;
  int q = lane >> 3;   // edge slot 0..7
  int p8 = lane & 7;   // channel octet / head
  if (HN != 0) {
    const float4* W4 = (const float4*)Wn;
    float4* ws4 = (float4*)ws;
    for (int k = t; k < 1024; k += 512) ws4[k] = W4[k];
    __syncthreads();
  }
  const int iA = blockIdx.x * 16 + (t >> 6) * 2;
  const int iB = iA + 1;

  int j0A = rowptr[iA], jeA = rowptr[iA + 1], jeB = rowptr[iB + 1];
  int j0B = jeA;
  float adA = (H == 8) ? a_dst[iA * 8 + p8] : a_dst[iA];
  float adB = (H == 8) ? a_dst[iB * 8 + p8] : a_dst[iB];
  float asSA = (H == 8) ? a_src[iA * 8 + p8] : a_src[iA];
  float asSB = (H == 8) ? a_src[iB * 8 + p8] : a_src[iB];
  float4 hsA = *(const float4*)&h[iA * 64 + 8 * p8];
  float4 hsB = *(const float4*)&h[iB * 64 + 8 * p8];

  int degA = jeA - j0A, degB = jeB - j0B;
  int sIdxA = 0, sIdxB = 0;
  if (degA > 0) {
    int li = j0A + lane;
    if (li > jeA - 1) li = jeA - 1;
    sIdxA = srcs[li];
  }
  if (degB > 0) {
    int li = j0B + lane;
    if (li > jeB - 1) li = jeB - 1;
    sIdxB = srcs[li];
  }
  int bA = degA < 64 ? degA : 64;
  int bB = degB < 64 ? degB : 64;
  int mx = bA > bB ? bA : bB;

  float denA = 0.f, denB = 0.f;
  float accA[8], accB[8];
#pragma unroll
  for (int c = 0; c < 8; ++c) { accA[c] = 0.f; accB[c] = 0.f; }

  for (int r0 = 0; r0 < mx; r0 += 16) {
    int svA[2], svB[2];
    float asvA[2], asvB[2];
    float4 hvA[2], hvB[2];
    bool doA = r0 < bA, doB = r0 < bB;
    if (doA) {
#pragma unroll
      for (int u = 0; u < 2; ++u) svA[u] = __shfl(sIdxA, r0 + u * 8 + q);
#pragma unroll
      for (int u = 0; u < 2; ++u)
        asvA[u] = (H == 8) ? a_src[svA[u] * 8 + p8] : a_src[svA[u]];
#pragma unroll
      for (int u = 0; u < 2; ++u)
        hvA[u] = *(const float4*)&h[svA[u] * 64 + 8 * p8];
    }
    if (doB) {
#pragma unroll
      for (int u = 0; u < 2; ++u) svB[u] = __shfl(sIdxB, r0 + u * 8 + q);
#pragma unroll
      for (int u = 0; u < 2; ++u)
        asvB[u] = (H == 8) ? a_src[svB[u] * 8 + p8] : a_src[svB[u]];
#pragma unroll
      for (int u = 0; u < 2; ++u)
        hvB[u] = *(const float4*)&h[svB[u] * 64 + 8 * p8];
    }
    if (doA) {
#pragma unroll
      for (int u = 0; u < 2; ++u) {
        int r = r0 + u * 8 + q;
        float ll = asvA[u] + adA;
        ll = (ll > 0.f) ? ll : 0.2f * ll;
        float ww = __expf(ll);
        ww = (r < bA) ? ww : 0.f;
        denA += ww;
        const __half2* hp = (const __half2*)&hvA[u];
        float2 f0 = __half22float2(hp[0]);
        float2 f1 = __half22float2(hp[1]);
        float2 f2 = __half22float2(hp[2]);
        float2 f3 = __half22float2(hp[3]);
        accA[0] = fmaf(ww, f0.x, accA[0]); accA[1] = fmaf(ww, f0.y, accA[1]);
        accA[2] = fmaf(ww, f1.x, accA[2]); accA[3] = fmaf(ww, f1.y, accA[3]);
        accA[4] = fmaf(ww, f2.x, accA[4]); accA[5] = fmaf(ww, f2.y, accA[5]);
        accA[6] = fmaf(ww, f3.x, accA[6]); accA[7] = fmaf(ww, f3.y, accA[7]);
      }
    }
    if (doB) {
#pragma unroll
      for (int u = 0; u < 2; ++u) {
        int r = r0 + u * 8 + q;
        float ll = asvB[u] + adB;
        ll = (ll > 0.f) ? ll : 0.2f * ll;
        float ww = __expf(ll);
        ww = (r < bB) ? ww : 0.f;
        denB += ww;
        const __half2* hp = (const __half2*)&hvB[u];
        float2 f0 = __half22float2(hp[0]);
        float2 f1 = __half22float2(hp[1]);
        float2 f2 = __half22float2(hp[2]);
        float2 f3 = __half22float2(hp[3]);
        accB[0] = fmaf(ww, f0.x, accB[0]); accB[1] = fmaf(ww, f0.y, accB[1]);
        accB[2] = fmaf(ww, f1.x, accB[2]); accB[3] = fmaf(ww, f1.y, accB[3]);
        accB[4] = fmaf(ww, f2.x, accB[4]); accB[5] = fmaf(ww, f2.y, accB[5]);
        accB[6] = fmaf(ww, f3.x, accB[6]); accB[7] = fmaf(ww, f3.y, accB[7]);
      }
    }
  }
  // rare tails (deg > 64)
  for (int b0 = 64; b0 < degA; b0 += 64) {
    int li = j0A + b0 + lane;
    if (li > jeA - 1) li = jeA - 1;
    int sIdx = srcs[li];
    int blkn = degA - b0;
    if (blkn > 64) blkn = 64;
    for (int r0 = 0; r0 < blkn; r0 += 16) {
#pragma unroll
      for (int u = 0; u < 2; ++u) {
        int r = r0 + u * 8 + q;
        int s = __shfl(sIdx, r);
        float av = (H == 8) ? a_src[s * 8 + p8] : a_src[s];
        float ll = av + adA;
        ll = (ll > 0.f) ? ll : 0.2f * ll;
        float ww = __expf(ll);
        ww = (r < blkn) ? ww : 0.f;
        float4 hv = *(const float4*)&h[s * 64 + 8 * p8];
        const __half2* hp = (const __half2*)&hv;
        float2 f0 = __half22float2(hp[0]);
        float2 f1 = __half22float2(hp[1]);
        float2 f2 = __half22float2(hp[2]);
        float2 f3 = __half22float2(hp[3]);
        denA += ww;
        accA[0] = fmaf(ww, f0.x, accA[0]); accA[1] = fmaf(ww, f0.y, accA[1]);
        accA[2] = fmaf(ww, f1.x, accA[2]); accA[3] = fmaf(ww, f1.y, accA[3]);
        accA[4] = fmaf(ww, f2.x, accA[4]); accA[5] = fmaf(ww, f2.y, accA[5]);
        accA[6] = fmaf(ww, f3.x, accA[6]); accA[7] = fmaf(ww, f3.y, accA[7]);
      }
    }
  }
  for (int b0 = 64; b0 < degB; b0 += 64) {
    int li = j0B + b0 + lane;
    if (li > jeB - 1) li = jeB - 1;
    int sIdx = srcs[li];
    int blkn = degB - b0;
    if (blkn > 64) blkn = 64;
    for (int r0 = 0; r0 < blkn; r0 += 16) {
#pragma unroll
      for (int u = 0; u < 2; ++u) {
        int r = r0 + u * 8 + q;
        int s = __shfl(sIdx, r);
        float av = (H == 8) ? a_src[s * 8 + p8] : a_src[s];
        float ll = av + adB;
        ll = (ll > 0.f) ? ll : 0.2f * ll;
        float ww = __expf(ll);
        ww = (r < blkn) ? ww : 0.f;
        float4 hv = *(const float4*)&h[s * 64 + 8 * p8];
        const __half2* hp = (const __half2*)&hv;
        float2 f0 = __half22float2(hp[0]);
        float2 f1 = __half22float2(hp[1]);
        float2 f2 = __half22float2(hp[2]);
        float2 f3 = __half22float2(hp[3]);
        denB += ww;
        accB[0] = fmaf(ww, f0.x, accB[0]); accB[1] = fmaf(ww, f0.y, accB[1]);
        accB[2] = fmaf(ww, f1.x, accB[2]); accB[3] = fmaf(ww, f1.y, accB[3]);
        accB[4] = fmaf(ww, f2.x, accB[4]); accB[5] = fmaf(ww, f2.y, accB[5]);
        accB[6] = fmaf(ww, f3.x, accB[6]); accB[7] = fmaf(ww, f3.y, accB[7]);
      }
    }
  }

  // reduce over the 8 edge-slot groups (q = bits 3..5 of lane)
#pragma unroll
  for (int m = 8; m <= 32; m <<= 1) {
    denA += __shfl_xor(denA, m);
    denB += __shfl_xor(denB, m);
#pragma unroll
    for (int c = 0; c < 8; ++c) {
      accA[c] += __shfl_xor(accA[c], m);
      accB[c] += __shfl_xor(accB[c], m);
    }
  }
  // self loops (per lane, post-reduction; identical across q groups)
  {
    float l = asSA + adA;
    l = (l > 0.f) ? l : 0.2f * l;
    float w = __expf(l);
    const __half2* hp = (const __half2*)&hsA;
    float2 f0 = __half22float2(hp[0]);
    float2 f1 = __half22float2(hp[1]);
    float2 f2 = __half22float2(hp[2]);
    float2 f3 = __half22float2(hp[3]);
    denA += w;
    accA[0] = fmaf(w, f0.x, accA[0]); accA[1] = fmaf(w, f0.y, accA[1]);
    accA[2] = fmaf(w, f1.x, accA[2]); accA[3] = fmaf(w, f1.y, accA[3]);
    accA[4] = fmaf(w, f2.x, accA[4]); accA[5] = fmaf(w, f2.y, accA[5]);
    accA[6] = fmaf(w, f3.x, accA[6]); accA[7] = fmaf(w, f3.y, accA[7]);
    l = asSB + adB;
    l = (l > 0.f) ? l : 0.2f * l;
    w = __expf(l);
    hp = (const __half2*)&hsB;
    f0 = __half22float2(hp[0]);
    f1 = __half22float2(hp[1]);
    f2 = __half22float2(hp[2]);
    f3 = __half22float2(hp[3]);
    denB += w;
    accB[0] = fmaf(w, f0.x, accB[0]); accB[1] = fmaf(w, f0.y, accB[1]);
    accB[2] = fmaf(w, f1.x, accB[2]); accB[3] = fmaf(w, f1.y, accB[3]);
    accB[4] = fmaf(w, f2.x, accB[4]); accB[5] = fmaf(w, f2.y, accB[5]);
    accB[6] = fmaf(w, f3.x, accB[6]); accB[7] = fmaf(w, f3.y, accB[7]);
  }
  float4 bv0 = *(const float4*)&bias[8 * p8];
  float4 bv1 = *(const float4*)&bias[8 * p8 + 4];
  float invA = 1.f / denA, invB = 1.f / denB;
  float oA[8], oB[8];
  const float* bb = &bv0.x;
#pragma unroll
  for (int c = 0; c < 4; ++c) {
    oA[c] = accA[c] * invA + ((const float*)&bv0)[c];
    oB[c] = accB[c] * invB + ((const float*)&bv0)[c];
    oA[c + 4] = accA[c + 4] * invA + ((const float*)&bv1)[c];
    oB[c + 4] = accB[c + 4] * invB + ((const float*)&bv1)[c];
  }
  (void)bb;
  if (RELU) {
#pragma unroll
    for (int c = 0; c < 8; ++c) {
      oA[c] = fmaxf(oA[c], 0.f);
      oB[c] = fmaxf(oB[c], 0.f);
    }
  }
  if (HN == 0) {
    if (q == 0) {
      *(float4*)&out_f[iA * 64 + 8 * p8] = make_float4(oA[0], oA[1], oA[2], oA[3]);
      *(float4*)&out_f[iA * 64 + 8 * p8 + 4] = make_float4(oA[4], oA[5], oA[6], oA[7]);
      *(float4*)&out_f[iB * 64 + 8 * p8] = make_float4(oB[0], oB[1], oB[2], oB[3]);
      *(float4*)&out_f[iB * 64 + 8 * p8 + 4] = make_float4(oB[4], oB[5], oB[6], oB[7]);
    }
    return;
  }
  // fused next GEMM: k = q*8 + kk (each q-group does 8 k-steps), reduce over q.
  const float4* ws4 = (const float4*)ws;
  float a2A[8], a2B[8];
#pragma unroll
  for (int c = 0; c < 8; ++c) { a2A[c] = 0.f; a2B[c] = 0.f; }
#pragma unroll
  for (int kk = 0; kk < 8; ++kk) {
    float okA = __shfl(oA[kk], q);  // lane q holds channels 8q..8q+7; reg kk = ch q*8+kk
    float okB = __shfl(oB[kk], q);
    int k = q * 8 + kk;
    float4 w0 = ws4[k * 16 + 2 * p8];
    float4 w1 = ws4[k * 16 + 2 * p8 + 1];
    a2A[0] = fmaf(okA, w0.x, a2A[0]); a2A[1] = fmaf(okA, w0.y, a2A[1]);
    a2A[2] = fmaf(okA, w0.z, a2A[2]); a2A[3] = fmaf(okA, w0.w, a2A[3]);
    a2A[4] = fmaf(okA, w1.x, a2A[4]); a2A[5] = fmaf(okA, w1.y, a2A[5]);
    a2A[6] = fmaf(okA, w1.z, a2A[6]); a2A[7] = fmaf(okA, w1.w, a2A[7]);
    a2B[0] = fmaf(okB, w0.x, a2B[0]); a2B[1] = fmaf(okB, w0.y, a2B[1]);
    a2B[2] = fmaf(okB, w0.z, a2B[2]); a2B[3] = fmaf(okB, w0.w, a2B[3]);
    a2B[4] = fmaf(okB, w1.x, a2B[4]); a2B[5] = fmaf(okB, w1.y, a2B[5]);
    a2B[6] = fmaf(okB, w1.z, a2B[6]); a2B[7] = fmaf(okB, w1.w, a2B[7]);
  }
#pragma unroll
  for (int m = 8; m <= 32; m <<= 1) {
#pragma unroll
    for (int c = 0; c < 8; ++c) {
      a2A[c] += __shfl_xor(a2A[c], m);
      a2B[c] += __shfl_xor(a2B[c], m);
    }
  }
  if (q == 0) {
    float4 stA, stB;
    ((__half2*)&stA)[0] = __floats2half2_rn(a2A[0], a2A[1]);
    ((__half2*)&stA)[1] = __floats2half2_rn(a2A[2], a2A[3]);
    ((__half2*)&stA)[2] = __floats2half2_rn(a2A[4], a2A[5]);
    ((__half2*)&stA)[3] = __floats2half2_rn(a2A[6], a2A[7]);
    ((__half2*)&stB)[0] = __floats2half2_rn(a2B[0], a2B[1]);
    ((__half2*)&stB)[1] = __floats2half2_rn(a2B[2], a2B[3]);
    ((__half2*)&stB)[2] = __floats2half2_rn(a2B[4], a2B[5]);
    ((__half2*)&stB)[3] = __floats2half2_rn(a2B[6], a2B[7]);
    *(float4*)&out_h[iA * 64 + 8 * p8] = stA;
    *(float4*)&out_h[iB * 64 + 8 * p8] = stB;
  }
  float4 an0 = *(const float4*)&asn[8 * p8];
  float4 an1 = *(const float4*)&asn[8 * p8 + 4];
  float4 ad0 = *(const float4*)&adn[8 * p8];
  float4 ad1 = *(const float4*)&adn[8 * p8 + 4];
  float tsA = a2A[0] * an0.x + a2A[1] * an0.y + a2A[2] * an0.z + a2A[3] * an0.w +
              a2A[4] * an1.x + a2A[5] * an1.y + a2A[6] * an1.z + a2A[7] * an1.w;
  float tdA = a2A[0] * ad0.x + a2A[1] * ad0.y + a2A[2] * ad0.z + a2A[3] * ad0.w +
              a2A[4] * ad1.x + a2A[5] * ad1.y + a2A[6] * ad1.z + a2A[7] * ad1.w;
  float tsB = a2B[0] * an0.x + a2B[1] * an0.y + a2B[2] * an0.z + a2B[3] * an0.w +
              a2B[4] * an1.x + a2B[5] * an1.y + a2B[6] * an1.z + a2B[7] * an1.w;
  float tdB = a2B[0] * ad0.x + a2B[1] * ad0.y + a2B[2] * ad0.z + a2B[3] * ad0.w +
              a2B[4] * ad1.x + a2B[5] * ad1.y + a2B[6] * ad1.z + a2B[7] * ad1.w;
  if (HN == 8) {
    // head = p8: in-lane sum is the whole head; write once per head.
    if (q == 0) {
      a_src_n[iA * 8 + p8] = tsA;
      a_dst_n[iA * 8 + p8] = tdA;
      a_src_n[iB * 8 + p8] = tsB;
      a_dst_n[iB * 8 + p8] = tdB;
    }
  } else {
#pragma unroll
    for (int off = 1; off < 8; off <<= 1) {
      tsA += __shfl_xor(tsA, off);
      tdA += __shfl_xor(tdA, off);
      tsB += __shfl_xor(tsB, off);
      tdB += __shfl_xor(tdB, off);
    }
    if (lane == 0) {
      a_src_n[iA] = tsA;
      a_dst_n[iA] = tdA;
      a_src_n[iB] = tsB;
      a_dst_n[iB] = tdB;
    }
  }
}

// ---------------- fused pool + readout: one block per graph ----------------

__global__ __launch_bounds__(256) void poolread_kernel(
    const float* __restrict__ xF, const int* __restrict__ batch,
    const float* __restrict__ Wm1, const float* __restrict__ bm1,
    const float* __restrict__ Wm2, const float* __restrict__ bm2,
    float* __restrict__ out) {
  __shared__ float sred[4][64];
  __shared__ int se[2];
  int g = blockIdx.x;
  int t = threadIdx.x;
  int w = t >> 6, c = t & 63;
  if (t < 2) {
    int target = g + t;
    int lo = 0, hi = NN;
    while (lo < hi) {
      int m = (lo + hi) >> 1;
      if (batch[m] < target) lo = m + 1;
      else hi = m;
    }
    se[t] = lo;
  }
  __syncthreads();
  int s = se[0], e = se[1];
  float acc = 0.f;
  for (int n = s + w; n < e; n += 4) acc += xF[n * 64 + c];
  sred[w][c] = acc;
  __syncthreads();
  if (w == 0) {
    float v = sred[0][c] + sred[1][c] + sred[2][c] + sred[3][c];
    float cv = fmaxf((float)(e - s), 1.f);
    float gv = v / cv;
    float a1 = 0.f;
#pragma unroll
    for (int k = 0; k < 64; ++k) {
      float bk = __shfl(gv, k);
      if (c < 32) a1 = fmaf(bk, Wm1[k * 32 + c], a1);
    }
    float m = 0.f;
    if (c < 32) {
      float hid = fmaxf(a1 + bm1[c], 0.f);
      m = hid * Wm2[c];
    }
#pragma unroll
    for (int off = 32; off >= 1; off >>= 1) m += __shfl_xor(m, off);
    if (c == 0) out[g] = m + bm2[0];
  }
}

// ---------------- launch ----------------

extern "C" void kernel_launch(void* const* d_in, const int* in_sizes, int n_in,
                              void* d_out, int out_size, void* d_ws, size_t ws_size,
                              hipStream_t stream) {
  const float* x0       = (const float*)d_in[0];
  const int*   edge_idx = (const int*)d_in[1];
  const int*   batch    = (const int*)d_in[3];
  const int*   dis_idx  = (const int*)d_in[6];
  const float* W1  = (const float*)d_in[7];
  const float* as1 = (const float*)d_in[8];
  const float* ad1 = (const float*)d_in[9];
  const float* b1  = (const float*)d_in[10];
  const float* W2  = (const float*)d_in[11];
  const float* as2 = (const float*)d_in[12];
  const float* ad2 = (const float*)d_in[13];
  const float* b2  = (const float*)d_in[14];
  const float* Wm1 = (const float*)d_in[19];
  const float* bm1 = (const float*)d_in[20];
  const float* Wm2 = (const float*)d_in[21];
  const float* bm2 = (const float*)d_in[22];
  float* out = (float*)d_out;

  char* ws = (char*)d_ws;
  size_t off = 0;
  auto alloc = [&](size_t bytes) {
    void* p = ws + off;
    off += (bytes + 255) & ~(size_t)255;
    return p;
  };
  __half* hA   = (__half*)alloc(NN * 64 * 2);
  __half* hB   = (__half*)alloc(NN * 64 * 2);
  float* xF    = (float*)alloc(NN * 64 * 4);
  float* asA   = (float*)alloc(NN * 8 * 4);
  float* adA   = (float*)alloc(NN * 8 * 4);
  float* asB   = (float*)alloc(NN * 8 * 4);
  float* adB   = (float*)alloc(NN * 8 * 4);
  int* rp_d    = (int*)alloc((NN + 1) * 4);
  int* s_d     = (int*)alloc(NE * 4);
  int* rp_e    = (int*)alloc((NN + 1) * 4);
  int* s_e     = (int*)alloc(NE * 4);
  int* totals  = (int*)alloc(2 * SCB * 4);
  char* zero0  = ws + off;
  int* cnt_d   = (int*)alloc(NN * 4);
  int* cur_d   = (int*)alloc(NN * 4);
  int* cnt_e   = (int*)alloc(NN * 4);
  int* cur_e   = (int*)alloc(NN * 4);
  size_t zbytes = (size_t)((char*)(ws + off) - zero0);

  const size_t SH = 64 * 64 * sizeof(float);
  const int NBG = NN / 8;   // 2500 (gemm, 512 thr)
  const int NBA = NN / 16;  // 1250 (agg, 512 thr, 2 nodes/wave)

  hipMemsetAsync(zero0, 0, zbytes, stream);
  hist_both_kernel<<<2 * HB, 256, 0, stream>>>(dis_idx + NE, edge_idx + NE,
                                               cnt_d, cnt_e);
  scan_local_kernel<<<2 * SCB, 256, 0, stream>>>(cnt_d, cnt_e, rp_d, rp_e, totals);
  scan_apply_kernel<<<2 * SCB, 256, 0, stream>>>(totals, rp_d, rp_e);
  scatter_both_kernel<<<2 * HB, 256, 0, stream>>>(dis_idx, edge_idx, rp_d, rp_e,
                                                  cur_d, cur_e, s_d, s_e);

  gemm_attn_kernel<<<NBG, 512, 0, stream>>>(x0, W1, as1, ad1, hA, asA, adA);

  for (int k = 0; k < 12; ++k) {
    const int* rp = (((k >> 1) & 1) == 0) ? rp_d : rp_e;
    const int* ss = (((k >> 1) & 1) == 0) ? s_d : s_e;
    if ((k & 1) == 0) {
      agg_fused_kernel<8, true, 1><<<NBA, 512, SH, stream>>>(
          hA, asA, adA, rp, ss, b1, hB, nullptr, W2, as2, ad2, asB, adB);
    } else if (k < 11) {
      agg_fused_kernel<1, false, 8><<<NBA, 512, SH, stream>>>(
          hB, asB, adB, rp, ss, b2, hA, nullptr, W1, as1, ad1, asA, adA);
    } else {
      agg_fused_kernel<1, false, 0><<<NBA, 512, 0, stream>>>(
          hB, asB, adB, rp, ss, b2, nullptr, xF, nullptr, nullptr, nullptr,
          nullptr, nullptr);
    }
  }

  poolread_kernel<<<NG, 256, 0, stream>>>(xF, batch, Wm1, bm1, Wm2, bm2, out);
}

// Round 12
// 373.273 us; speedup vs baseline: 1.3428x; 1.0617x over previous
//
#include <hip/hip_runtime.h>
#include <hip/hip_fp16.h>

#define NN 20000
#define NE 320000
#define NG 256
#define HB 313
#define SCB 80

typedef _Float16 f16x8 __attribute__((ext_vector_type(8)));
typedef float f32x4 __attribute__((ext_vector_type(4)));

// ---------------- CSR build ----------------

__global__ __launch_bounds__(256) void hist_both_kernel(
    const int* __restrict__ dis_dst, const int* __restrict__ edge_dst,
    int* __restrict__ cnt_d, int* __restrict__ cnt_e) {
  int b = blockIdx.x;
  const int* dst = (b < HB) ? dis_dst : edge_dst;
  int* cnt = (b < HB) ? cnt_d : cnt_e;
  int base = ((b < HB) ? b : b - HB) * 1024 + threadIdx.x;
#pragma unroll
  for (int u = 0; u < 4; ++u) {
    int e = base + u * 256;
    if (e < NE) atomicAdd(&cnt[dst[e]], 1);
  }
}

__global__ __launch_bounds__(256) void scan_local_kernel(
    const int* __restrict__ cnt_d, const int* __restrict__ cnt_e,
    int* __restrict__ rp_d, int* __restrict__ rp_e, int* __restrict__ totals) {
  int b = blockIdx.x;
  const int* counts = (b < SCB) ? cnt_d : cnt_e;
  int* rp = (b < SCB) ? rp_d : rp_e;
  int base = ((b < SCB) ? b : b - SCB) * 256;
  int t = threadIdx.x;
  int lane = t & 63;
  int w = t >> 6;
  int idx = base + t;
  int v = (idx < NN) ? counts[idx] : 0;
  int incl = v;
#pragma unroll
  for (int off = 1; off < 64; off <<= 1) {
    int g = __shfl_up(incl, off);
    if (lane >= off) incl += g;
  }
  __shared__ int wsum[4];
  if (lane == 63) wsum[w] = incl;
  __syncthreads();
  int woff = 0;
  for (int j = 0; j < 4; ++j)
    if (j < w) woff += wsum[j];
  if (idx < NN) rp[idx] = woff + incl - v;
  if (t == 255) totals[b] = woff + incl;
}

__global__ __launch_bounds__(256) void scan_apply_kernel(
    const int* __restrict__ totals, int* __restrict__ rp_d,
    int* __restrict__ rp_e) {
  int b = blockIdx.x;
  int set = (b < SCB) ? 0 : 1;
  int lb = (b < SCB) ? b : b - SCB;
  const int* tt = totals + set * SCB;
  int t = threadIdx.x;
  __shared__ int soff, stot;
  if (t < 64) {
    int lane = t;
    int v = (lane < lb) ? tt[lane] : 0;
    int a = (lane < SCB) ? tt[lane] : 0;
    int l2 = 64 + lane;
    if (l2 < SCB) {
      if (l2 < lb) v += tt[l2];
      a += tt[l2];
    }
#pragma unroll
    for (int off = 1; off < 64; off <<= 1) {
      v += __shfl_xor(v, off);
      a += __shfl_xor(a, off);
    }
    if (lane == 0) { soff = v; stot = a; }
  }
  __syncthreads();
  int* rp = (set == 0) ? rp_d : rp_e;
  int idx = lb * 256 + t;
  if (idx < NN) rp[idx] += soff;
  if (t == 0 && lb == SCB - 1) rp[NN] = stot;
}

__global__ __launch_bounds__(256) void scatter_both_kernel(
    const int* __restrict__ dis_idx, const int* __restrict__ edge_idx,
    const int* __restrict__ rp_d, const int* __restrict__ rp_e,
    int* __restrict__ cur_d, int* __restrict__ cur_e,
    int* __restrict__ s_d, int* __restrict__ s_e) {
  int b = blockIdx.x;
  const int* ei = (b < HB) ? dis_idx : edge_idx;
  const int* rp = (b < HB) ? rp_d : rp_e;
  int* cur = (b < HB) ? cur_d : cur_e;
  int* sout = (b < HB) ? s_d : s_e;
  int base = ((b < HB) ? b : b - HB) * 1024 + threadIdx.x;
#pragma unroll
  for (int u = 0; u < 4; ++u) {
    int e = base + u * 256;
    if (e < NE) {
      int d = ei[NE + e];
      int pos = rp[d] + atomicAdd(&cur[d], 1);
      sout[pos] = ei[e];
    }
  }
}

// ---------------- precompute: M = W2@W1, vs2/vd2 = W2@as2/ad2, bM = b2@W1 ----

__global__ __launch_bounds__(256) void precomp_kernel(
    const float* __restrict__ W1, const float* __restrict__ W2,
    const float* __restrict__ as2, const float* __restrict__ ad2,
    const float* __restrict__ b2, float* __restrict__ M,
    float* __restrict__ vs2, float* __restrict__ vd2, float* __restrict__ bM) {
  __shared__ float w1s[4096], w2s[4096];
  int t = threadIdx.x;
  for (int i = t; i < 1024; i += 256) {
    ((float4*)w1s)[i] = ((const float4*)W1)[i];
    ((float4*)w2s)[i] = ((const float4*)W2)[i];
  }
  __syncthreads();
  int b = blockIdx.x;
  if (b < 16) {
    int idx = b * 256 + t;
    int k = idx >> 6, n = idx & 63;
    float s = 0.f;
#pragma unroll
    for (int j = 0; j < 64; ++j) s = fmaf(w2s[k * 64 + j], w1s[j * 64 + n], s);
    M[idx] = s;
  } else {
    if (t < 64) {
      float s = 0.f;
      for (int c = 0; c < 64; ++c) s = fmaf(w2s[t * 64 + c], as2[c], s);
      vs2[t] = s;
    } else if (t < 128) {
      int k = t - 64;
      float s = 0.f;
      for (int c = 0; c < 64; ++c) s = fmaf(w2s[k * 64 + c], ad2[c], s);
      vd2[k] = s;
    } else if (t < 192) {
      int n = t - 128;
      float s = 0.f;
      for (int k = 0; k < 64; ++k) s = fmaf(b2[k], w1s[k * 64 + n], s);
      bM[n] = s;
    }
  }
}

// ---------------- first GEMM + attention sums ----------------

__global__ __launch_bounds__(512) void gemm_attn_kernel(
    const float* __restrict__ x, const float* __restrict__ W,
    const float* __restrict__ att_src, const float* __restrict__ att_dst,
    __half* __restrict__ h, float* __restrict__ a_src, float* __restrict__ a_dst) {
  __shared__ float ws[64 * 64];
  int t = threadIdx.x;
  int lr = t >> 6;
  int c = t & 63;
  int n = blockIdx.x * 8 + lr;
  const float4* W4 = (const float4*)W;
  float4* ws4 = (float4*)ws;
  for (int k = t; k < 1024; k += 512) ws4[k] = W4[k];
  float xv = x[n * 64 + c];
  __syncthreads();
  float acc = 0.f;
#pragma unroll
  for (int k = 0; k < 64; ++k) {
    float xk = __shfl(xv, k);
    acc = fmaf(xk, ws[k * 64 + c], acc);
  }
  h[n * 64 + c] = __float2half(acc);
  float ts = acc * att_src[c];
  float td = acc * att_dst[c];
#pragma unroll
  for (int off = 1; off < 8; off <<= 1) {
    ts += __shfl_xor(ts, off);
    td += __shfl_xor(td, off);
  }
  if ((c & 7) == 0) {
    a_src[n * 8 + (c >> 3)] = ts;
    a_dst[n * 8 + (c >> 3)] = td;
  }
}

// ---------------- shared main aggregation (r8 layout, 2 nodes/wave) ---------
// lane = (half, p): channels {2p,2p+1}; half 0 even edges, half 1 odd edges.
// Returns normalized (no bias) outputs for both nodes.
template <int H>
__device__ __forceinline__ void agg_main(
    const __half* __restrict__ h, const float* __restrict__ a_src,
    const float* __restrict__ a_dst, const int* __restrict__ rowptr,
    const int* __restrict__ srcs, int iA, int iB, int lane, int half, int p,
    int hd, float& OxA, float& OyA, float& OxB, float& OyB) {
  int j0A = rowptr[iA], jeA = rowptr[iA + 1], jeB = rowptr[iB + 1];
  int j0B = jeA;
  float adA = a_dst[iA * H + hd], adB = a_dst[iB * H + hd];
  float asSA = a_src[iA * H + hd], asSB = a_src[iB * H + hd];
  __half2 hsA = *(const __half2*)&h[iA * 64 + 2 * p];
  __half2 hsB = *(const __half2*)&h[iB * 64 + 2 * p];

  int degA = jeA - j0A, degB = jeB - j0B;
  int sIdxA = 0, sIdxB = 0;
  if (degA > 0) {
    int li = j0A + lane;
    if (li > jeA - 1) li = jeA - 1;
    sIdxA = srcs[li];
  }
  if (degB > 0) {
    int li = j0B + lane;
    if (li > jeB - 1) li = jeB - 1;
    sIdxB = srcs[li];
  }
  int bA = degA < 64 ? degA : 64;
  int bB = degB < 64 ? degB : 64;
  int mx = bA > bB ? bA : bB;

  float denA = 0.f, axA = 0.f, ayA = 0.f;
  float denB = 0.f, axB = 0.f, ayB = 0.f;

  for (int r0 = 0; r0 < mx; r0 += 16) {
    int svA[8], svB[8];
    float asvA[8], asvB[8];
    __half2 hvA[8], hvB[8];
    bool doA = r0 < bA, doB = r0 < bB;
    if (doA) {
#pragma unroll
      for (int u = 0; u < 8; ++u) svA[u] = __shfl(sIdxA, r0 + 2 * u + half);
#pragma unroll
      for (int u = 0; u < 8; ++u) asvA[u] = a_src[svA[u] * H + hd];
#pragma unroll
      for (int u = 0; u < 8; ++u)
        hvA[u] = *(const __half2*)&h[svA[u] * 64 + 2 * p];
    }
    if (doB) {
#pragma unroll
      for (int u = 0; u < 8; ++u) svB[u] = __shfl(sIdxB, r0 + 2 * u + half);
#pragma unroll
      for (int u = 0; u < 8; ++u) asvB[u] = a_src[svB[u] * H + hd];
#pragma unroll
      for (int u = 0; u < 8; ++u)
        hvB[u] = *(const __half2*)&h[svB[u] * 64 + 2 * p];
    }
    if (doA) {
#pragma unroll
      for (int u = 0; u < 8; ++u) {
        int r = r0 + 2 * u + half;
        float ll = asvA[u] + adA;
        ll = (ll > 0.f) ? ll : 0.2f * ll;
        float ww = __expf(ll);
        ww = (r < bA) ? ww : 0.f;
        float2 hf = __half22float2(hvA[u]);
        denA += ww;
        axA = fmaf(ww, hf.x, axA);
        ayA = fmaf(ww, hf.y, ayA);
      }
    }
    if (doB) {
#pragma unroll
      for (int u = 0; u < 8; ++u) {
        int r = r0 + 2 * u + half;
        float ll = asvB[u] + adB;
        ll = (ll > 0.f) ? ll : 0.2f * ll;
        float ww = __expf(ll);
        ww = (r < bB) ? ww : 0.f;
        float2 hf = __half22float2(hvB[u]);
        denB += ww;
        axB = fmaf(ww, hf.x, axB);
        ayB = fmaf(ww, hf.y, ayB);
      }
    }
  }
  for (int b0 = 64; b0 < degA; b0 += 64) {
    int li = j0A + b0 + lane;
    if (li > jeA - 1) li = jeA - 1;
    int sIdx = srcs[li];
    int blkn = degA - b0;
    if (blkn > 64) blkn = 64;
    for (int r0 = 0; r0 < blkn; r0 += 16) {
#pragma unroll
      for (int u = 0; u < 8; ++u) {
        int r = r0 + 2 * u + half;
        int s = __shfl(sIdx, r);
        float ll = a_src[s * H + hd] + adA;
        ll = (ll > 0.f) ? ll : 0.2f * ll;
        float ww = __expf(ll);
        ww = (r < blkn) ? ww : 0.f;
        float2 hf = __half22float2(*(const __half2*)&h[s * 64 + 2 * p]);
        denA += ww;
        axA = fmaf(ww, hf.x, axA);
        ayA = fmaf(ww, hf.y, ayA);
      }
    }
  }
  for (int b0 = 64; b0 < degB; b0 += 64) {
    int li = j0B + b0 + lane;
    if (li > jeB - 1) li = jeB - 1;
    int sIdx = srcs[li];
    int blkn = degB - b0;
    if (blkn > 64) blkn = 64;
    for (int r0 = 0; r0 < blkn; r0 += 16) {
#pragma unroll
      for (int u = 0; u < 8; ++u) {
        int r = r0 + 2 * u + half;
        int s = __shfl(sIdx, r);
        float ll = a_src[s * H + hd] + adB;
        ll = (ll > 0.f) ? ll : 0.2f * ll;
        float ww = __expf(ll);
        ww = (r < blkn) ? ww : 0.f;
        float2 hf = __half22float2(*(const __half2*)&h[s * 64 + 2 * p]);
        denB += ww;
        axB = fmaf(ww, hf.x, axB);
        ayB = fmaf(ww, hf.y, ayB);
      }
    }
  }

  denA += __shfl_xor(denA, 32);
  axA += __shfl_xor(axA, 32);
  ayA += __shfl_xor(ayA, 32);
  denB += __shfl_xor(denB, 32);
  axB += __shfl_xor(axB, 32);
  ayB += __shfl_xor(ayB, 32);
  {
    float l = asSA + adA;
    l = (l > 0.f) ? l : 0.2f * l;
    float w = __expf(l);
    float2 hf = __half22float2(hsA);
    denA += w;
    axA = fmaf(w, hf.x, axA);
    ayA = fmaf(w, hf.y, ayA);
    l = asSB + adB;
    l = (l > 0.f) ? l : 0.2f * l;
    w = __expf(l);
    hf = __half22float2(hsB);
    denB += w;
    axB = fmaf(w, hf.x, axB);
    ayB = fmaf(w, hf.y, ayB);
  }
  float invA = 1.f / denA, invB = 1.f / denB;
  OxA = axA * invA;
  OyA = ayA * invA;
  OxB = axB * invB;
  OyB = ayB * invB;
}

// ---------------- conv1: agg(H=8) + relu + a2 dots + MFMA GEMM (o1 @ G) ----
__global__ __launch_bounds__(512) void agg1_kernel(
    const __half* __restrict__ h, const float* __restrict__ a1s,
    const float* __restrict__ a1d, const int* __restrict__ rowptr,
    const int* __restrict__ srcs, const float* __restrict__ b1,
    const float* __restrict__ G, const float* __restrict__ vs2,
    const float* __restrict__ vd2, __half* __restrict__ g_out,
    float* __restrict__ a2s, float* __restrict__ a2d) {
  __shared__ __align__(16) __half Bt[64 * 64];
  __shared__ __align__(16) __half o16[16 * 64];
  int t = threadIdx.x;
  int lane = t & 63;
  int half = lane >> 5;
  int p = lane & 31;
  // stage Bt = G^T as fp16
  for (int idx = t; idx < 4096; idx += 512) {
    int k = idx >> 6, n = idx & 63;
    Bt[n * 64 + k] = __float2half(G[idx]);
  }
  const int hd = p >> 2;
  const int iA = blockIdx.x * 16 + (t >> 6) * 2;
  const int iB = iA + 1;

  float oxA, oyA, oxB, oyB;
  agg_main<8>(h, a1s, a1d, rowptr, srcs, iA, iB, lane, half, p, hd,
              oxA, oyA, oxB, oyB);
  float bx = b1[2 * p], by = b1[2 * p + 1];
  oxA = fmaxf(oxA + bx, 0.f);
  oyA = fmaxf(oyA + by, 0.f);
  oxB = fmaxf(oxB + bx, 0.f);
  oyB = fmaxf(oyB + by, 0.f);

  // a2 dots (H=1 next): a2 = o1 . vs2 / vd2
  float vsx = vs2[2 * p], vsy = vs2[2 * p + 1];
  float vdx = vd2[2 * p], vdy = vd2[2 * p + 1];
  float tsA = oxA * vsx + oyA * vsy;
  float tdA = oxA * vdx + oyA * vdy;
  float tsB = oxB * vsx + oyB * vsy;
  float tdB = oxB * vdx + oyB * vdy;
#pragma unroll
  for (int off = 1; off < 32; off <<= 1) {
    tsA += __shfl_xor(tsA, off);
    tdA += __shfl_xor(tdA, off);
    tsB += __shfl_xor(tsB, off);
    tdB += __shfl_xor(tdB, off);
  }
  if (lane == 0) {
    a2s[iA] = tsA;
    a2d[iA] = tdA;
    a2s[iB] = tsB;
    a2d[iB] = tdB;
  }
  // stage o1 tile
  if (half == 0) {
    int ln = (t >> 6) * 2;
    *(__half2*)&o16[ln * 64 + 2 * p] = __floats2half2_rn(oxA, oyA);
    *(__half2*)&o16[(ln + 1) * 64 + 2 * p] = __floats2half2_rn(oxB, oyB);
  }
  __syncthreads();
  int w = t >> 6;
  if (w < 4) {
    int m = lane & 15, g4 = lane >> 4;
    f16x8 a0 = *(const f16x8*)&o16[m * 64 + g4 * 8];
    f16x8 a1v = *(const f16x8*)&o16[m * 64 + 32 + g4 * 8];
    f16x8 b0 = *(const f16x8*)&Bt[(w * 16 + m) * 64 + g4 * 8];
    f16x8 b1v = *(const f16x8*)&Bt[(w * 16 + m) * 64 + 32 + g4 * 8];
    f32x4 acc = {0.f, 0.f, 0.f, 0.f};
    acc = __builtin_amdgcn_mfma_f32_16x16x32_f16(a0, b0, acc, 0, 0, 0);
    acc = __builtin_amdgcn_mfma_f32_16x16x32_f16(a1v, b1v, acc, 0, 0, 0);
    int ch = w * 16 + m;
    int nb = blockIdx.x * 16 + g4 * 4;
#pragma unroll
    for (int r = 0; r < 4; ++r)
      g_out[(nb + r) * 64 + ch] = __float2half(acc[r]);
  }
}

// ---------------- conv2: agg(H=1) + bias; LAST: f32 out; else fp16 + a1 dots
template <int LAST>
__global__ __launch_bounds__(512) void agg2_kernel(
    const __half* __restrict__ g, const float* __restrict__ a2s,
    const float* __restrict__ a2d, const int* __restrict__ rowptr,
    const int* __restrict__ srcs, const float* __restrict__ biasv,
    const float* __restrict__ as1, const float* __restrict__ ad1,
    __half* __restrict__ out_h, float* __restrict__ out_f,
    float* __restrict__ a1s_n, float* __restrict__ a1d_n) {
  int t = threadIdx.x;
  int lane = t & 63;
  int half = lane >> 5;
  int p = lane & 31;
  const int iA = blockIdx.x * 16 + (t >> 6) * 2;
  const int iB = iA + 1;

  float oxA, oyA, oxB, oyB;
  agg_main<1>(g, a2s, a2d, rowptr, srcs, iA, iB, lane, half, p, 0,
              oxA, oyA, oxB, oyB);
  float bx = biasv[2 * p], by = biasv[2 * p + 1];
  oxA += bx; oyA += by; oxB += bx; oyB += by;

  if (LAST) {
    if (half == 0) {
      *(float2*)&out_f[iA * 64 + 2 * p] = make_float2(oxA, oyA);
      *(float2*)&out_f[iB * 64 + 2 * p] = make_float2(oxB, oyB);
    }
    return;
  }
  if (half == 0) {
    *(__half2*)&out_h[iA * 64 + 2 * p] = __floats2half2_rn(oxA, oyA);
    *(__half2*)&out_h[iB * 64 + 2 * p] = __floats2half2_rn(oxB, oyB);
  }
  // a1 dots per head (hd = p>>2, 8 channels per head = 4 ch-pairs)
  float asx = as1[2 * p], asy = as1[2 * p + 1];
  float adx = ad1[2 * p], ady = ad1[2 * p + 1];
  float tsA = oxA * asx + oyA * asy;
  float tdA = oxA * adx + oyA * ady;
  float tsB = oxB * asx + oyB * asy;
  float tdB = oxB * adx + oyB * ady;
#pragma unroll
  for (int off = 1; off < 4; off <<= 1) {
    tsA += __shfl_xor(tsA, off);
    tdA += __shfl_xor(tdA, off);
    tsB += __shfl_xor(tsB, off);
    tdB += __shfl_xor(tdB, off);
  }
  if (half == 0 && (p & 3) == 0) {
    int hd = p >> 2;
    a1s_n[iA * 8 + hd] = tsA;
    a1d_n[iA * 8 + hd] = tdA;
    a1s_n[iB * 8 + hd] = tsB;
    a1d_n[iB * 8 + hd] = tdB;
  }
}

// ---------------- fused pool + readout ----------------

__global__ __launch_bounds__(256) void poolread_kernel(
    const float* __restrict__ xF, const int* __restrict__ batch,
    const float* __restrict__ Wm1, const float* __restrict__ bm1,
    const float* __restrict__ Wm2, const float* __restrict__ bm2,
    float* __restrict__ out) {
  __shared__ float sred[4][64];
  __shared__ int se[2];
  int g = blockIdx.x;
  int t = threadIdx.x;
  int w = t >> 6, c = t & 63;
  if (t < 2) {
    int target = g + t;
    int lo = 0, hi = NN;
    while (lo < hi) {
      int m = (lo + hi) >> 1;
      if (batch[m] < target) lo = m + 1;
      else hi = m;
    }
    se[t] = lo;
  }
  __syncthreads();
  int s = se[0], e = se[1];
  float acc = 0.f;
  for (int n = s + w; n < e; n += 4) acc += xF[n * 64 + c];
  sred[w][c] = acc;
  __syncthreads();
  if (w == 0) {
    float v = sred[0][c] + sred[1][c] + sred[2][c] + sred[3][c];
    float cv = fmaxf((float)(e - s), 1.f);
    float gv = v / cv;
    float a1 = 0.f;
#pragma unroll
    for (int k = 0; k < 64; ++k) {
      float bk = __shfl(gv, k);
      if (c < 32) a1 = fmaf(bk, Wm1[k * 32 + c], a1);
    }
    float m = 0.f;
    if (c < 32) {
      float hid = fmaxf(a1 + bm1[c], 0.f);
      m = hid * Wm2[c];
    }
#pragma unroll
    for (int off = 32; off >= 1; off >>= 1) m += __shfl_xor(m, off);
    if (c == 0) out[g] = m + bm2[0];
  }
}

// ---------------- launch ----------------

extern "C" void kernel_launch(void* const* d_in, const int* in_sizes, int n_in,
                              void* d_out, int out_size, void* d_ws, size_t ws_size,
                              hipStream_t stream) {
  const float* x0       = (const float*)d_in[0];
  const int*   edge_idx = (const int*)d_in[1];
  const int*   batch    = (const int*)d_in[3];
  const int*   dis_idx  = (const int*)d_in[6];
  const float* W1  = (const float*)d_in[7];
  const float* as1 = (const float*)d_in[8];
  const float* ad1 = (const float*)d_in[9];
  const float* b1  = (const float*)d_in[10];
  const float* W2  = (const float*)d_in[11];
  const float* as2 = (const float*)d_in[12];
  const float* ad2 = (const float*)d_in[13];
  const float* b2  = (const float*)d_in[14];
  const float* Wm1 = (const float*)d_in[19];
  const float* bm1 = (const float*)d_in[20];
  const float* Wm2 = (const float*)d_in[21];
  const float* bm2 = (const float*)d_in[22];
  float* out = (float*)d_out;

  char* ws = (char*)d_ws;
  size_t off = 0;
  auto alloc = [&](size_t bytes) {
    void* p = ws + off;
    off += (bytes + 255) & ~(size_t)255;
    return p;
  };
  __half* hA   = (__half*)alloc(NN * 64 * 2);   // conv1 input
  __half* gB   = (__half*)alloc(NN * 64 * 2);   // conv2 input (premultiplied)
  float* xF    = (float*)alloc(NN * 64 * 4);
  float* a1s   = (float*)alloc(NN * 8 * 4);
  float* a1d   = (float*)alloc(NN * 8 * 4);
  float* a2s   = (float*)alloc(NN * 4);
  float* a2d   = (float*)alloc(NN * 4);
  float* Mbuf  = (float*)alloc(4096 * 4);
  float* vs2   = (float*)alloc(64 * 4);
  float* vd2   = (float*)alloc(64 * 4);
  float* bMv   = (float*)alloc(64 * 4);
  int* rp_d    = (int*)alloc((NN + 1) * 4);
  int* s_d     = (int*)alloc(NE * 4);
  int* rp_e    = (int*)alloc((NN + 1) * 4);
  int* s_e     = (int*)alloc(NE * 4);
  int* totals  = (int*)alloc(2 * SCB * 4);
  char* zero0  = ws + off;
  int* cnt_d   = (int*)alloc(NN * 4);
  int* cur_d   = (int*)alloc(NN * 4);
  int* cnt_e   = (int*)alloc(NN * 4);
  int* cur_e   = (int*)alloc(NN * 4);
  size_t zbytes = (size_t)((char*)(ws + off) - zero0);

  const int NBG = NN / 8;   // 2500
  const int NBA = NN / 16;  // 1250

  hipMemsetAsync(zero0, 0, zbytes, stream);
  precomp_kernel<<<17, 256, 0, stream>>>(W1, W2, as2, ad2, b2, Mbuf, vs2, vd2, bMv);
  hist_both_kernel<<<2 * HB, 256, 0, stream>>>(dis_idx + NE, edge_idx + NE,
                                               cnt_d, cnt_e);
  scan_local_kernel<<<2 * SCB, 256, 0, stream>>>(cnt_d, cnt_e, rp_d, rp_e, totals);
  scan_apply_kernel<<<2 * SCB, 256, 0, stream>>>(totals, rp_d, rp_e);
  scatter_both_kernel<<<2 * HB, 256, 0, stream>>>(dis_idx, edge_idx, rp_d, rp_e,
                                                  cur_d, cur_e, s_d, s_e);

  gemm_attn_kernel<<<NBG, 512, 0, stream>>>(x0, W1, as1, ad1, hA, a1s, a1d);

  for (int k = 0; k < 12; ++k) {
    const int* rp = (((k >> 1) & 1) == 0) ? rp_d : rp_e;
    const int* ss = (((k >> 1) & 1) == 0) ? s_d : s_e;
    if ((k & 1) == 0) {
      // conv1: agg H=8 + relu, epilogue GEMM with M (or W2 at k=10) + a2 dots
      const float* G = (k == 10) ? W2 : Mbuf;
      agg1_kernel<<<NBA, 512, 0, stream>>>(hA, a1s, a1d, rp, ss, b1, G, vs2,
                                           vd2, gB, a2s, a2d);
    } else if (k < 11) {
      // conv2: agg H=1 on premultiplied g, bias bM, emit next h + a1 dots
      agg2_kernel<0><<<NBA, 512, 0, stream>>>(gB, a2s, a2d, rp, ss, bMv, as1,
                                              ad1, hA, nullptr, a1s, a1d);
    } else {
      // last conv2: g is o1@W2, bias b2, f32 out
      agg2_kernel<1><<<NBA, 512, 0, stream>>>(gB, a2s, a2d, rp, ss, b2, nullptr,
                                              nullptr, nullptr, xF, nullptr,
                                              nullptr);
    }
  }

  poolread_kernel<<<NG, 256, 0, stream>>>(xF, batch, Wm1, bm1, Wm2, bm2, out);
}